// Round 11
// baseline (129.297 us; speedup 1.0000x reference)
//
#include <hip/hip_runtime.h>
#include <hip/hip_bf16.h>

// Problem constants: B=4, T=2048, C(n_embd)=1024, H(head)=128
#define Bn 4
#define Tn 2048
#define Cn 1024
#define Hn 128
#define Mn (Bn*Tn)   // 8192 rows of X
#define SCHUNKS 4    // s-split across blocks in attention
#define SCHUNK  (Tn/SCHUNKS)   // 512

typedef _Float16 f16;
typedef __attribute__((ext_vector_type(4))) _Float16 f16x4;  // 2 VGPRs
typedef __attribute__((ext_vector_type(8))) _Float16 f16x8;  // 4 VGPRs
typedef __attribute__((ext_vector_type(4))) float f32x4;

// ---------------------------------------------------------------------------
// Kernel 1: transpose + convert weights [C][H] fp32 -> fused [3*H][C] fp16.
// LDS 64x64 tile transpose: coalesced float4 reads AND f16x8 writes.
// grid = (Cn/64, Hn/64, 3) = (16,2,3) = 96 blocks, 256 threads.
// ---------------------------------------------------------------------------
__global__ __launch_bounds__(256) void prep_w(const float* __restrict__ Wk,
                                              const float* __restrict__ Wq,
                                              const float* __restrict__ Wv,
                                              f16* __restrict__ Wt) {
    __shared__ __align__(16) f16 T[64 * 72];   // [c][h], stride 72
    const int w = blockIdx.z;
    const float* W = (w == 0) ? Wk : (w == 1) ? Wq : Wv;
    const int c0 = blockIdx.x * 64, h0 = blockIdx.y * 64;
    const int tid = threadIdx.x;

    for (int i = 0; i < 4; i++) {
        int ci = tid + 256 * i;
        int row = ci >> 4, c4 = ci & 15;
        float4 x = *(const float4*)(W + (c0 + row) * Hn + h0 + c4 * 4);
        f16x4 v = { (f16)x.x, (f16)x.y, (f16)x.z, (f16)x.w };
        *(f16x4*)(&T[row * 72 + c4 * 4]) = v;
    }
    __syncthreads();
    for (int i = 0; i < 2; i++) {
        int ci = tid + 256 * i;
        int h = ci >> 3, cc = ci & 7;
        f16x8 v;
        for (int j = 0; j < 8; j++) v[j] = T[(cc * 8 + j) * 72 + h];
        *(f16x8*)(Wt + (w * Hn + h0 + h) * Cn + c0 + cc * 8) = v;
    }
}

// ---------------------------------------------------------------------------
// Kernel 2: fused QKV projection.  [k|q|v] = X @ [Wk|Wq|Wv] + bias, k *= 1/32.
// grid = (Mn/64, 2) = 256 blocks (1/CU), 256 threads (4 waves, 1m x 4n).
// BM=64, BN=192, BK=64. Per wave: mt=4 x nt=3 -> 0.58 LDS-reads/MFMA (was
// 0.83 at mt=2). Register prefetch of next K-iter's X/Wt hides latency.
// Epilogue via LDS: k/q row-major f16x8 stores; v stored transposed into vT.
// ---------------------------------------------------------------------------
__global__ __launch_bounds__(256, 1) void qkv_gemm(const float* __restrict__ X,
                                                   const f16* __restrict__ Wt,
                                                   const float* __restrict__ bk,
                                                   const float* __restrict__ bq,
                                                   const float* __restrict__ bv,
                                                   f16* __restrict__ pk,
                                                   f16* __restrict__ pq,
                                                   f16* __restrict__ vT) {
    __shared__ __align__(16) char smem[36864];
    f16* As = (f16*)smem;                  // [64][72]   9216 B
    f16* Bs = (f16*)(smem + 9216);         // [192][72] 27648 B

    const int tid  = threadIdx.x;
    const int r0   = blockIdx.x * 64;
    const int ns   = blockIdx.y;           // 0: n 0..191, 1: n 192..383
    const int lane = tid & 63, wn = tid >> 6;     // 4 waves = 4 n-slots
    const int quad = lane >> 4, l16 = lane & 15;

    f32x4 acc[4][3] = {};

    // prefetch K-iter 0: X 1024 float4 (4/thread), Wt 1536 f16x8 (6/thread)
    float4 xreg[4];
    f16x8  wreg[6];
    for (int i = 0; i < 4; i++) {
        int ci = tid + 256 * i;
        xreg[i] = *(const float4*)(X + (r0 + (ci >> 4)) * Cn + (ci & 15) * 4);
    }
    for (int i = 0; i < 6; i++) {
        int ci = tid + 256 * i;
        wreg[i] = *(const f16x8*)(Wt + (ns * 192 + (ci >> 3)) * Cn + (ci & 7) * 8);
    }

    for (int kit = 0; kit < 16; kit++) {
        __syncthreads();   // previous iter's fragment reads done
        for (int i = 0; i < 4; i++) {
            int ci = tid + 256 * i;
            float4 x = xreg[i];
            f16x4 v = { (f16)x.x, (f16)x.y, (f16)x.z, (f16)x.w };
            *(f16x4*)(&As[(ci >> 4) * 72 + (ci & 15) * 4]) = v;
        }
        for (int i = 0; i < 6; i++) {
            int ci = tid + 256 * i;
            *(f16x8*)(&Bs[(ci >> 3) * 72 + (ci & 7) * 8]) = wreg[i];
        }
        __syncthreads();
        if (kit + 1 < 16) {
            int k1 = (kit + 1) * 64;
            for (int i = 0; i < 4; i++) {
                int ci = tid + 256 * i;
                xreg[i] = *(const float4*)(X + (r0 + (ci >> 4)) * Cn + k1 + (ci & 15) * 4);
            }
            for (int i = 0; i < 6; i++) {
                int ci = tid + 256 * i;
                wreg[i] = *(const f16x8*)(Wt + (ns * 192 + (ci >> 3)) * Cn + k1 + (ci & 7) * 8);
            }
        }
        for (int ks = 0; ks < 2; ks++) {
            int kk = ks * 32;
            f16x8 af[4], bf[3];
            for (int mt = 0; mt < 4; mt++)
                af[mt] = *(const f16x8*)(&As[(mt * 16 + l16) * 72 + kk + quad * 8]);
            for (int nt = 0; nt < 3; nt++)
                bf[nt] = *(const f16x8*)(&Bs[(wn * 48 + nt * 16 + l16) * 72 + kk + quad * 8]);
            for (int mt = 0; mt < 4; mt++)
                for (int nt = 0; nt < 3; nt++)
                    acc[mt][nt] = __builtin_amdgcn_mfma_f32_16x16x32_f16(
                        af[mt], bf[nt], acc[mt][nt], 0, 0, 0);
        }
    }
    __syncthreads();

    // ---- epilogue via LDS: E [64 rows][200] f16 (reuses staging smem) ----
    f16* E = (f16*)smem;
    for (int nt = 0; nt < 3; nt++) {
        int n0 = ns * 192 + wn * 48 + nt * 16;
        int wsel = n0 >> 7;
        int col = (n0 & 127) + l16;
        const float* bias = (wsel == 0) ? bk : (wsel == 1) ? bq : bv;
        float bval = bias[col];
        float scale = (wsel == 0) ? 0.03125f : 1.0f;   // fold C^-0.5 into k
        for (int mt = 0; mt < 4; mt++)
            for (int r = 0; r < 4; r++) {
                int mrow = mt * 16 + quad * 4 + r;
                E[mrow * 200 + wn * 48 + nt * 16 + l16] =
                    (f16)((acc[mt][nt][r] + bval) * scale);
            }
    }
    __syncthreads();

    if (ns == 0) {
        // 192 cols = k(0..127) | q(0..63): 64 rows x 24 chunks = 1536, 6/thr
        for (int i = 0; i < 6; i++) {
            int ci = tid + 256 * i;
            int row = ci / 24, c = ci % 24;
            f16x8 v = *(const f16x8*)(&E[row * 200 + c * 8]);
            int gn = c * 8;                      // 0..191
            f16* dst = (gn < 128) ? (pk + (r0 + row) * Hn + gn)
                                  : (pq + (r0 + row) * Hn + (gn - 128));
            *(f16x8*)dst = v;
        }
    } else {
        // local cols 0..63 = q(64..127): 64 rows x 8 chunks = 512, 2/thr
        for (int i = 0; i < 2; i++) {
            int ci = tid + 256 * i;
            int row = ci >> 3, c = ci & 7;
            f16x8 v = *(const f16x8*)(&E[row * 200 + c * 8]);
            *(f16x8*)(pq + (r0 + row) * Hn + 64 + c * 8) = v;
        }
        // local cols 64..191 = v -> vT[b][h][s]: 128h x 8 s-chunks, 4/thr
        int b = r0 >> 11, sg = r0 & 2047;
        for (int i = 0; i < 4; i++) {
            int ci = tid + 256 * i;
            int h = ci >> 3, sc = ci & 7;
            f16x8 v;
            for (int j = 0; j < 8; j++)
                v[j] = E[(sc * 8 + j) * 200 + 64 + h];
            *(f16x8*)(vT + (b * Hn + h) * Tn + sg + sc * 8) = v;
        }
    }
}

// ---------------------------------------------------------------------------
// Kernel 3: flash attention over an s-chunk. 128 t per block (32 t/wave, two
// 16-t tiles). Single LDS buffer (R6-proven). Register prefetch of next
// iter's q/vT hides global latency behind compute.
// grid = (Tn/128, SCHUNKS, Bn) = (16,4,4) = 256 blocks, 256 threads (4 waves).
// ---------------------------------------------------------------------------
__global__ __launch_bounds__(256, 2) void attn_kernel(const f16* __restrict__ pk,
                                                      const f16* __restrict__ pq,
                                                      const f16* __restrict__ vT,
                                                      f16* __restrict__ pO,
                                                      float* __restrict__ pm,
                                                      float* __restrict__ pl) {
    __shared__ __align__(16) char smem[36864];
    f16* Bq = (f16*)smem;                 // [64][136] q rows (s-major), 17408 B
    f16* Vt = (f16*)(smem + 17408);       // [128][72]  vT tile (h-major), 18432 B

    const int tid  = threadIdx.x;
    const int tblk = blockIdx.x, c = blockIdx.y, b = blockIdx.z;
    const int t0   = tblk * 128;
    const int lane = tid & 63, wid = tid >> 6;
    const int quad = lane >> 4, l16 = lane & 15;
    const int tw   = t0 + wid * 32;                // wave's 32-t base

    const f16* kp = pk + b * Tn * Hn;
    const f16* qp = pq + b * Tn * Hn;
    const f16* vp = vT + b * Hn * Tn;

    // hoist k fragments: 2 t-tiles x 4 K32-steps, B[n=t(l16)][k=h]
    f16x8 kfr[2][4];
    for (int tt = 0; tt < 2; tt++)
        for (int ks = 0; ks < 4; ks++)
            kfr[tt][ks] = *(const f16x8*)(kp + (tw + tt * 16 + l16) * Hn + ks * 32 + quad * 8);

    float m_i[2] = { -3e38f, -3e38f }, l_i[2] = { 0.0f, 0.0f };
    f32x4 accO[2][8] = {};

    // prefetch iter 0
    f16x8 qreg[4], vreg[4];
    {
        const int s0 = c * SCHUNK;
        for (int i = 0; i < 4; i++) {
            int ci = tid + 256 * i;
            qreg[i] = *(const f16x8*)(qp + (s0 + (ci >> 4)) * Hn + (ci & 15) * 8);
            vreg[i] = *(const f16x8*)(vp + (ci >> 3) * Tn + s0 + (ci & 7) * 8);
        }
    }

    for (int si = 0; si < SCHUNK / 64; si++) {
        __syncthreads();   // LDS free (previous iter's reads done)
        for (int i = 0; i < 4; i++) {
            int ci = tid + 256 * i;
            *(f16x8*)(&Bq[(ci >> 4) * 136 + (ci & 15) * 8]) = qreg[i];
            *(f16x8*)(&Vt[(ci >> 3) * 72 + (ci & 7) * 8]) = vreg[i];
        }
        __syncthreads();
        if (si + 1 < SCHUNK / 64) {
            const int s1 = c * SCHUNK + (si + 1) * 64;
            for (int i = 0; i < 4; i++) {
                int ci = tid + 256 * i;
                qreg[i] = *(const f16x8*)(qp + (s1 + (ci >> 4)) * Hn + (ci & 15) * 8);
                vreg[i] = *(const f16x8*)(vp + (ci >> 3) * Tn + s1 + (ci & 7) * 8);
            }
        }

        // S^T tiles: A = q rows (m=s), B = k frags (n=t). af shared across tt.
        f32x4 accS[2][4] = {};
        for (int ks = 0; ks < 4; ks++) {
            int kk = ks * 32;
            for (int st = 0; st < 4; st++) {
                f16x8 af = *(const f16x8*)(&Bq[(st * 16 + l16) * 136 + kk + quad * 8]);
                accS[0][st] = __builtin_amdgcn_mfma_f32_16x16x32_f16(af, kfr[0][ks], accS[0][st], 0, 0, 0);
                accS[1][st] = __builtin_amdgcn_mfma_f32_16x16x32_f16(af, kfr[1][ks], accS[1][st], 0, 0, 0);
            }
        }

        // online softmax in registers: row = t = l16; s over quad x reg x st.
        f16x4 pf[2][4];
        for (int tt = 0; tt < 2; tt++) {
            float mloc = -3e38f;
            for (int st = 0; st < 4; st++)
                for (int r = 0; r < 4; r++) mloc = fmaxf(mloc, accS[tt][st][r]);
            mloc = fmaxf(mloc, __shfl_xor(mloc, 16));
            mloc = fmaxf(mloc, __shfl_xor(mloc, 32));
            float mnew = fmaxf(m_i[tt], mloc);
            float alpha = __expf(m_i[tt] - mnew);
            m_i[tt] = mnew;
            float psum = 0.0f;
            for (int st = 0; st < 4; st++) {
                f32x4 p;
                for (int r = 0; r < 4; r++) {
                    p[r] = __expf(accS[tt][st][r] - mnew);
                    psum += p[r];
                }
                pf[tt][st] = { (f16)p[0], (f16)p[1], (f16)p[2], (f16)p[3] };
            }
            psum += __shfl_xor(psum, 16);
            psum += __shfl_xor(psum, 32);
            l_i[tt] = l_i[tt] * alpha + psum;
            for (int ht = 0; ht < 8; ht++)
                for (int r = 0; r < 4; r++) accO[tt][ht][r] *= alpha;
        }

        // O^T += Vt . P  (K=16). av shared across tt.
        for (int st = 0; st < 4; st++) {
            for (int ht = 0; ht < 8; ht++) {
                f16x4 av = *(const f16x4*)(&Vt[(ht * 16 + l16) * 72 + st * 16 + quad * 4]);
                accO[0][ht] = __builtin_amdgcn_mfma_f32_16x16x16f16(av, pf[0][st], accO[0][ht], 0, 0, 0);
                accO[1][ht] = __builtin_amdgcn_mfma_f32_16x16x16f16(av, pf[1][st], accO[1][ht], 0, 0, 0);
            }
        }
    }

    // epilogue: per t-tile, transpose O^T (h=quad*4+reg, t=l16) via LDS,
    // store f16 partials. Uniform control flow -> barriers are safe.
    for (int tt = 0; tt < 2; tt++) {
        __syncthreads();
        float* ep = (float*)smem + wid * 2048;     // 16t x 128h per wave (8 KB)
        for (int ht = 0; ht < 8; ht++)
            for (int r = 0; r < 4; r++)
                ep[(ht * 16 + quad * 4 + r) * 16 + l16] = accO[tt][ht][r];
        __syncthreads();
        {
            int t = lane >> 2, hq = lane & 3;
            int tgl = tw + tt * 16 + t;
            f16* dst = pO + ((size_t)(c * Bn + b) * Tn + tgl) * Hn + hq * 32;
            for (int g = 0; g < 4; g++) {          // 4 x f16x8 = 32 h
                f16x8 v;
                for (int j = 0; j < 8; j++)
                    v[j] = (f16)ep[(hq * 32 + g * 8 + j) * 16 + t];
                *(f16x8*)(dst + g * 8) = v;
            }
        }
        if (quad == 0) {
            pm[(c * Bn + b) * Tn + tw + tt * 16 + l16] = m_i[tt];
            pl[(c * Bn + b) * Tn + tw + tt * 16 + l16] = l_i[tt];
        }
    }
}

// ---------------------------------------------------------------------------
// Kernel 4: merge SCHUNKS partials. thread -> (b,t, 8 h's). Coalesced.
// grid = 512 blocks x 256 threads (one thread per (t, 8h) unit).
// ---------------------------------------------------------------------------
__global__ __launch_bounds__(256) void merge_kernel(const f16* __restrict__ pO,
                                                    const float* __restrict__ pm,
                                                    const float* __restrict__ pl,
                                                    float* __restrict__ out) {
    int gid = blockIdx.x * 256 + threadIdx.x;   // 0..131071
    int tg  = gid >> 4;                         // b*Tn + t  (0..8191)
    int hs  = (gid & 15) * 8;                   // 8 h per thread
    float mc[SCHUNKS], lc[SCHUNKS];
    float M = -3e38f;
    for (int cI = 0; cI < SCHUNKS; cI++) {
        mc[cI] = pm[cI * (Bn * Tn) + tg];
        lc[cI] = pl[cI * (Bn * Tn) + tg];
        M = fmaxf(M, mc[cI]);
    }
    float L = 0.0f, wc[SCHUNKS];
    for (int cI = 0; cI < SCHUNKS; cI++) {
        wc[cI] = __expf(mc[cI] - M);
        L += wc[cI] * lc[cI];
    }
    float inv = 1.0f / L;
    float o[8] = {};
    for (int cI = 0; cI < SCHUNKS; cI++) {
        const f16* src = pO + ((size_t)cI * Bn * Tn + tg) * Hn + hs;
        f16x8 v = *(const f16x8*)src;
        float w = wc[cI];
        for (int j = 0; j < 8; j++) o[j] += w * (float)v[j];
    }
    float* dst = out + (size_t)tg * Hn + hs;
    float4 v0 = { o[0] * inv, o[1] * inv, o[2] * inv, o[3] * inv };
    float4 v1 = { o[4] * inv, o[5] * inv, o[6] * inv, o[7] * inv };
    *(float4*)dst = v0;
    *(float4*)(dst + 4) = v1;
}

extern "C" void kernel_launch(void* const* d_in, const int* in_sizes, int n_in,
                              void* d_out, int out_size, void* d_ws, size_t ws_size,
                              hipStream_t stream) {
    const float* X  = (const float*)d_in[0];
    const float* Wk = (const float*)d_in[1];
    const float* bk = (const float*)d_in[2];
    const float* Wq = (const float*)d_in[3];
    const float* bq = (const float*)d_in[4];
    const float* Wv = (const float*)d_in[5];
    const float* bv = (const float*)d_in[6];
    float* out = (float*)d_out;

    // ws layout (bytes):
    //   Wt [384][1024] f16        @ 0           (786,432)
    //   pk [8192][128] f16        @ 786,432     (2,097,152)
    //   pq [8192][128] f16        @ 2,883,584   (2,097,152)
    //   vT [4][128][2048] f16     @ 4,980,736   (2,097,152)
    //   pO [4][4][2048][128] f16  @ 7,077,888   (8,388,608)
    //   pm [4][4][2048] f32       @ 15,466,496  (131,072)
    //   pl [4][4][2048] f32       @ 15,597,568  (131,072)   total ~15.7 MB
    char* base = (char*)d_ws;
    f16*   Wt = (f16*)(base);
    f16*   pk = (f16*)(base + 786432);
    f16*   pq = (f16*)(base + 2883584);
    f16*   vT = (f16*)(base + 4980736);
    f16*   pO = (f16*)(base + 7077888);
    float* pm = (float*)(base + 15466496);
    float* pl = (float*)(base + 15597568);

    prep_w<<<dim3(Cn / 64, Hn / 64, 3), 256, 0, stream>>>(Wk, Wq, Wv, Wt);
    qkv_gemm<<<dim3(Mn / 64, 2), 256, 0, stream>>>(X, Wt, bk, bq, bv, pk, pq, vT);
    attn_kernel<<<dim3(Tn / 128, SCHUNKS, Bn), 256, 0, stream>>>(pk, pq, vT, pO, pm, pl);
    merge_kernel<<<dim3(512), 256, 0, stream>>>(pO, pm, pl, out);
}

// Round 13
// 129.085 us; speedup vs baseline: 1.0016x; 1.0016x over previous
//
#include <hip/hip_runtime.h>
#include <hip/hip_bf16.h>

// Problem constants: B=4, T=2048, C(n_embd)=1024, H(head)=128
#define Bn 4
#define Tn 2048
#define Cn 1024
#define Hn 128
#define Mn (Bn*Tn)   // 8192 rows of X
#define SCHUNKS 4    // s-split across blocks in attention
#define SCHUNK  (Tn/SCHUNKS)   // 512

typedef _Float16 f16;
typedef __attribute__((ext_vector_type(4))) _Float16 f16x4;  // 2 VGPRs
typedef __attribute__((ext_vector_type(8))) _Float16 f16x8;  // 4 VGPRs
typedef __attribute__((ext_vector_type(4))) float f32x4;

// ---------------------------------------------------------------------------
// Kernel 1: transpose + convert weights [C][H] fp32 -> fused [3*H][C] fp16.
// LDS 64x64 tile transpose: coalesced float4 reads AND f16x8 writes.
// grid = (Cn/64, Hn/64, 3) = (16,2,3) = 96 blocks, 256 threads.
// ---------------------------------------------------------------------------
__global__ __launch_bounds__(256) void prep_w(const float* __restrict__ Wk,
                                              const float* __restrict__ Wq,
                                              const float* __restrict__ Wv,
                                              f16* __restrict__ Wt) {
    __shared__ __align__(16) f16 T[64 * 72];   // [c][h], stride 72
    const int w = blockIdx.z;
    const float* W = (w == 0) ? Wk : (w == 1) ? Wq : Wv;
    const int c0 = blockIdx.x * 64, h0 = blockIdx.y * 64;
    const int tid = threadIdx.x;

    for (int i = 0; i < 4; i++) {
        int ci = tid + 256 * i;
        int row = ci >> 4, c4 = ci & 15;
        float4 x = *(const float4*)(W + (c0 + row) * Hn + h0 + c4 * 4);
        f16x4 v = { (f16)x.x, (f16)x.y, (f16)x.z, (f16)x.w };
        *(f16x4*)(&T[row * 72 + c4 * 4]) = v;
    }
    __syncthreads();
    for (int i = 0; i < 2; i++) {
        int ci = tid + 256 * i;
        int h = ci >> 3, cc = ci & 7;
        f16x8 v;
        for (int j = 0; j < 8; j++) v[j] = T[(cc * 8 + j) * 72 + h];
        *(f16x8*)(Wt + (w * Hn + h0 + h) * Cn + c0 + cc * 8) = v;
    }
}

// ---------------------------------------------------------------------------
// Kernel 2: fused QKV projection.  [k|q|v] = X @ [Wk|Wq|Wv] + bias, k *= 1/32.
// grid = (Mn/64, 2) = 256 blocks, 512 threads (8 waves = 2/SIMD).
// BM=64, BN=192, BK=64, wave grid 2m x 4n.
// Epilogue via LDS: k/q row-major f16x8 stores; v stored transposed into vT.
// ---------------------------------------------------------------------------
__global__ __launch_bounds__(512) void qkv_gemm(const float* __restrict__ X,
                                                const f16* __restrict__ Wt,
                                                const float* __restrict__ bk,
                                                const float* __restrict__ bq,
                                                const float* __restrict__ bv,
                                                f16* __restrict__ pk,
                                                f16* __restrict__ pq,
                                                f16* __restrict__ vT) {
    __shared__ __align__(16) char smem[36864];
    f16* As = (f16*)smem;                  // [64][72]
    f16* Bs = (f16*)(smem + 9216);         // [192][72]

    const int tid  = threadIdx.x;
    const int r0   = blockIdx.x * 64;
    const int ns   = blockIdx.y;           // 0: n 0..191, 1: n 192..383
    const int lane = tid & 63, wid = tid >> 6;
    const int quad = lane >> 4, l16 = lane & 15;
    const int wm = wid >> 2, wn = wid & 3;

    f32x4 acc[2][3] = {};

    for (int k0 = 0; k0 < Cn; k0 += 64) {
        for (int i = 0; i < 2; i++) {
            int ci = tid + 512 * i;
            int row = ci >> 4, c4 = ci & 15;
            float4 x = *(const float4*)(X + (r0 + row) * Cn + k0 + c4 * 4);
            f16x4 v = { (f16)x.x, (f16)x.y, (f16)x.z, (f16)x.w };
            *(f16x4*)(&As[row * 72 + c4 * 4]) = v;
        }
        for (int i = 0; i < 3; i++) {
            int ci = tid + 512 * i;
            int row = ci >> 3, cc = ci & 7;
            *(f16x8*)(&Bs[row * 72 + cc * 8]) =
                *(const f16x8*)(Wt + (ns * 192 + row) * Cn + k0 + cc * 8);
        }
        __syncthreads();
        for (int ks = 0; ks < 2; ks++) {
            int kk = ks * 32;
            f16x8 af[2], bf[3];
            for (int mt = 0; mt < 2; mt++)
                af[mt] = *(const f16x8*)(&As[(wm * 32 + mt * 16 + l16) * 72 + kk + quad * 8]);
            for (int nt = 0; nt < 3; nt++)
                bf[nt] = *(const f16x8*)(&Bs[(wn * 48 + nt * 16 + l16) * 72 + kk + quad * 8]);
            for (int mt = 0; mt < 2; mt++)
                for (int nt = 0; nt < 3; nt++)
                    acc[mt][nt] = __builtin_amdgcn_mfma_f32_16x16x32_f16(
                        af[mt], bf[nt], acc[mt][nt], 0, 0, 0);
        }
        __syncthreads();
    }

    // ---- epilogue via LDS: E [64 rows][200] f16 (reuses staging smem) ----
    f16* E = (f16*)smem;
    for (int nt = 0; nt < 3; nt++) {
        int n0 = ns * 192 + wn * 48 + nt * 16;
        int wsel = n0 >> 7;
        int col = (n0 & 127) + l16;
        const float* bias = (wsel == 0) ? bk : (wsel == 1) ? bq : bv;
        float bval = bias[col];
        float scale = (wsel == 0) ? 0.03125f : 1.0f;   // fold C^-0.5 into k
        for (int mt = 0; mt < 2; mt++)
            for (int r = 0; r < 4; r++) {
                int mrow = wm * 32 + mt * 16 + quad * 4 + r;
                E[mrow * 200 + wn * 48 + nt * 16 + l16] =
                    (f16)((acc[mt][nt][r] + bval) * scale);
            }
    }
    __syncthreads();

    if (ns == 0) {
        for (int i = 0; i < 3; i++) {
            int ci = tid + 512 * i;
            int row = ci / 24, c = ci % 24;
            f16x8 v = *(const f16x8*)(&E[row * 200 + c * 8]);
            int gn = c * 8;                      // 0..191
            f16* dst = (gn < 128) ? (pk + (r0 + row) * Hn + gn)
                                  : (pq + (r0 + row) * Hn + (gn - 128));
            *(f16x8*)dst = v;
        }
    } else {
        {
            int ci = tid;
            int row = ci >> 3, c = ci & 7;
            f16x8 v = *(const f16x8*)(&E[row * 200 + c * 8]);
            *(f16x8*)(pq + (r0 + row) * Hn + 64 + c * 8) = v;
        }
        int b = r0 >> 11, sg = r0 & 2047;
        for (int i = 0; i < 2; i++) {
            int ci = tid + 512 * i;
            int h = ci >> 3, sc = ci & 7;
            f16x8 v;
            for (int j = 0; j < 8; j++)
                v[j] = E[(sc * 8 + j) * 200 + 64 + h];
            *(f16x8*)(vT + (b * Hn + h) * Tn + sg + sc * 8) = v;
        }
    }
}

// ---------------------------------------------------------------------------
// Kernel 3: flash attention over an s-chunk. 128 t per block (32 t/wave, two
// 16-t tiles). Single LDS buffer, DIRECT staging (global load -> ds_write
// between the two barriers; no cross-iteration register carry -- R12's
// post-timing divergence implicated the prefetch pattern, removed here).
// grid = (Tn/128, SCHUNKS, Bn) = (16,4,4) = 256 blocks, 256 threads (4 waves).
// ---------------------------------------------------------------------------
__global__ __launch_bounds__(256, 2) void attn_kernel(const f16* __restrict__ pk,
                                                      const f16* __restrict__ pq,
                                                      const f16* __restrict__ vT,
                                                      f16* __restrict__ pO,
                                                      float* __restrict__ pm,
                                                      float* __restrict__ pl) {
    __shared__ __align__(16) char smem[36864];
    f16* Bq = (f16*)smem;                 // [64][136] q rows (s-major), 17408 B
    f16* Vt = (f16*)(smem + 17408);       // [128][72]  vT tile (h-major), 18432 B

    const int tid  = threadIdx.x;
    const int tblk = blockIdx.x, c = blockIdx.y, b = blockIdx.z;
    const int t0   = tblk * 128;
    const int lane = tid & 63, wid = tid >> 6;
    const int quad = lane >> 4, l16 = lane & 15;
    const int tw   = t0 + wid * 32;                // wave's 32-t base

    const f16* kp = pk + b * Tn * Hn;
    const f16* qp = pq + b * Tn * Hn;
    const f16* vp = vT + b * Hn * Tn;

    // hoist k fragments: 2 t-tiles x 4 K32-steps, B[n=t(l16)][k=h]
    f16x8 kfr[2][4];
    for (int tt = 0; tt < 2; tt++)
        for (int ks = 0; ks < 4; ks++)
            kfr[tt][ks] = *(const f16x8*)(kp + (tw + tt * 16 + l16) * Hn + ks * 32 + quad * 8);

    float m_i[2] = { -3e38f, -3e38f }, l_i[2] = { 0.0f, 0.0f };
    f32x4 accO[2][8] = {};

    for (int si = 0; si < SCHUNK / 64; si++) {
        const int s0 = c * SCHUNK + si * 64;
        __syncthreads();   // previous iter's LDS reads retired
        for (int i = 0; i < 4; i++) {
            int ci = tid + 256 * i;
            f16x8 qv = *(const f16x8*)(qp + (s0 + (ci >> 4)) * Hn + (ci & 15) * 8);
            f16x8 vv = *(const f16x8*)(vp + (ci >> 3) * Tn + s0 + (ci & 7) * 8);
            *(f16x8*)(&Bq[(ci >> 4) * 136 + (ci & 15) * 8]) = qv;
            *(f16x8*)(&Vt[(ci >> 3) * 72 + (ci & 7) * 8]) = vv;
        }
        __syncthreads();

        // S^T tiles: A = q rows (m=s), B = k frags (n=t). af shared across tt.
        f32x4 accS[2][4] = {};
        for (int ks = 0; ks < 4; ks++) {
            int kk = ks * 32;
            for (int st = 0; st < 4; st++) {
                f16x8 af = *(const f16x8*)(&Bq[(st * 16 + l16) * 136 + kk + quad * 8]);
                accS[0][st] = __builtin_amdgcn_mfma_f32_16x16x32_f16(af, kfr[0][ks], accS[0][st], 0, 0, 0);
                accS[1][st] = __builtin_amdgcn_mfma_f32_16x16x32_f16(af, kfr[1][ks], accS[1][st], 0, 0, 0);
            }
        }

        // online softmax in registers: row = t = l16; s over quad x reg x st.
        f16x4 pf[2][4];
        for (int tt = 0; tt < 2; tt++) {
            float mloc = -3e38f;
            for (int st = 0; st < 4; st++)
                for (int r = 0; r < 4; r++) mloc = fmaxf(mloc, accS[tt][st][r]);
            mloc = fmaxf(mloc, __shfl_xor(mloc, 16));
            mloc = fmaxf(mloc, __shfl_xor(mloc, 32));
            float mnew = fmaxf(m_i[tt], mloc);
            float alpha = __expf(m_i[tt] - mnew);
            m_i[tt] = mnew;
            float psum = 0.0f;
            for (int st = 0; st < 4; st++) {
                f32x4 p;
                for (int r = 0; r < 4; r++) {
                    p[r] = __expf(accS[tt][st][r] - mnew);
                    psum += p[r];
                }
                pf[tt][st] = { (f16)p[0], (f16)p[1], (f16)p[2], (f16)p[3] };
            }
            psum += __shfl_xor(psum, 16);
            psum += __shfl_xor(psum, 32);
            l_i[tt] = l_i[tt] * alpha + psum;
            for (int ht = 0; ht < 8; ht++)
                for (int r = 0; r < 4; r++) accO[tt][ht][r] *= alpha;
        }

        // O^T += Vt . P  (K=16). av shared across tt.
        for (int st = 0; st < 4; st++) {
            for (int ht = 0; ht < 8; ht++) {
                f16x4 av = *(const f16x4*)(&Vt[(ht * 16 + l16) * 72 + st * 16 + quad * 4]);
                accO[0][ht] = __builtin_amdgcn_mfma_f32_16x16x16f16(av, pf[0][st], accO[0][ht], 0, 0, 0);
                accO[1][ht] = __builtin_amdgcn_mfma_f32_16x16x16f16(av, pf[1][st], accO[1][ht], 0, 0, 0);
            }
        }
    }

    // epilogue: per t-tile, transpose O^T (h=quad*4+reg, t=l16) via LDS,
    // store f16 partials. Uniform control flow -> barriers are safe.
    for (int tt = 0; tt < 2; tt++) {
        __syncthreads();
        float* ep = (float*)smem + wid * 2048;     // 16t x 128h per wave (8 KB)
        for (int ht = 0; ht < 8; ht++)
            for (int r = 0; r < 4; r++)
                ep[(ht * 16 + quad * 4 + r) * 16 + l16] = accO[tt][ht][r];
        __syncthreads();
        {
            int t = lane >> 2, hq = lane & 3;
            int tgl = tw + tt * 16 + t;
            f16* dst = pO + ((size_t)(c * Bn + b) * Tn + tgl) * Hn + hq * 32;
            for (int g = 0; g < 4; g++) {          // 4 x f16x8 = 32 h
                f16x8 v;
                for (int j = 0; j < 8; j++)
                    v[j] = (f16)ep[(hq * 32 + g * 8 + j) * 16 + t];
                *(f16x8*)(dst + g * 8) = v;
            }
        }
        if (quad == 0) {
            pm[(c * Bn + b) * Tn + tw + tt * 16 + l16] = m_i[tt];
            pl[(c * Bn + b) * Tn + tw + tt * 16 + l16] = l_i[tt];
        }
    }
}

// ---------------------------------------------------------------------------
// Kernel 4: merge SCHUNKS partials. thread -> (b,t, 8 h's). Coalesced.
// grid = 512 blocks x 256 threads (one thread per (t, 8h) unit).
// ---------------------------------------------------------------------------
__global__ __launch_bounds__(256) void merge_kernel(const f16* __restrict__ pO,
                                                    const float* __restrict__ pm,
                                                    const float* __restrict__ pl,
                                                    float* __restrict__ out) {
    int gid = blockIdx.x * 256 + threadIdx.x;   // 0..131071
    int tg  = gid >> 4;                         // b*Tn + t  (0..8191)
    int hs  = (gid & 15) * 8;                   // 8 h per thread
    float mc[SCHUNKS], lc[SCHUNKS];
    float M = -3e38f;
    for (int cI = 0; cI < SCHUNKS; cI++) {
        mc[cI] = pm[cI * (Bn * Tn) + tg];
        lc[cI] = pl[cI * (Bn * Tn) + tg];
        M = fmaxf(M, mc[cI]);
    }
    float L = 0.0f, wc[SCHUNKS];
    for (int cI = 0; cI < SCHUNKS; cI++) {
        wc[cI] = __expf(mc[cI] - M);
        L += wc[cI] * lc[cI];
    }
    float inv = 1.0f / L;
    float o[8] = {};
    for (int cI = 0; cI < SCHUNKS; cI++) {
        const f16* src = pO + ((size_t)cI * Bn * Tn + tg) * Hn + hs;
        f16x8 v = *(const f16x8*)src;
        float w = wc[cI];
        for (int j = 0; j < 8; j++) o[j] += w * (float)v[j];
    }
    float* dst = out + (size_t)tg * Hn + hs;
    float4 v0 = { o[0] * inv, o[1] * inv, o[2] * inv, o[3] * inv };
    float4 v1 = { o[4] * inv, o[5] * inv, o[6] * inv, o[7] * inv };
    *(float4*)dst = v0;
    *(float4*)(dst + 4) = v1;
}

extern "C" void kernel_launch(void* const* d_in, const int* in_sizes, int n_in,
                              void* d_out, int out_size, void* d_ws, size_t ws_size,
                              hipStream_t stream) {
    const float* X  = (const float*)d_in[0];
    const float* Wk = (const float*)d_in[1];
    const float* bk = (const float*)d_in[2];
    const float* Wq = (const float*)d_in[3];
    const float* bq = (const float*)d_in[4];
    const float* Wv = (const float*)d_in[5];
    const float* bv = (const float*)d_in[6];
    float* out = (float*)d_out;

    // ws layout (bytes):
    //   Wt [384][1024] f16        @ 0           (786,432)
    //   pk [8192][128] f16        @ 786,432     (2,097,152)
    //   pq [8192][128] f16        @ 2,883,584   (2,097,152)
    //   vT [4][128][2048] f16     @ 4,980,736   (2,097,152)
    //   pO [4][4][2048][128] f16  @ 7,077,888   (8,388,608)
    //   pm [4][4][2048] f32       @ 15,466,496  (131,072)
    //   pl [4][4][2048] f32       @ 15,597,568  (131,072)   total ~15.7 MB
    char* base = (char*)d_ws;
    f16*   Wt = (f16*)(base);
    f16*   pk = (f16*)(base + 786432);
    f16*   pq = (f16*)(base + 2883584);
    f16*   vT = (f16*)(base + 4980736);
    f16*   pO = (f16*)(base + 7077888);
    float* pm = (float*)(base + 15466496);
    float* pl = (float*)(base + 15597568);

    prep_w<<<dim3(Cn / 64, Hn / 64, 3), 256, 0, stream>>>(Wk, Wq, Wv, Wt);
    qkv_gemm<<<dim3(Mn / 64, 2), 512, 0, stream>>>(X, Wt, bk, bq, bv, pk, pq, vT);
    attn_kernel<<<dim3(Tn / 128, SCHUNKS, Bn), 256, 0, stream>>>(pk, pq, vT, pO, pm, pl);
    merge_kernel<<<dim3(512), 256, 0, stream>>>(pO, pm, pl, out);
}